// Round 1
// baseline (1165.478 us; speedup 1.0000x reference)
//
#include <hip/hip_runtime.h>
#include <hip/hip_bf16.h>
#include <stdint.h>

#define S_LEN 2048
#define NROW  4096            // B*S
#define DQKV  3072            // 2048 Q + 512 K + 512 V

typedef unsigned short u16;
typedef __attribute__((ext_vector_type(8))) short bf16x8;
typedef __attribute__((ext_vector_type(4))) float f32x4;

__device__ __forceinline__ float bf2f(u16 v) {
  unsigned int u = ((unsigned int)v) << 16;
  return __builtin_bit_cast(float, u);
}
__device__ __forceinline__ u16 f2bf(float f) {
  unsigned int u = __builtin_bit_cast(unsigned int, f);
  u += 0x7FFFu + ((u >> 16) & 1u);
  return (u16)(u >> 16);
}
__device__ __forceinline__ void async16(const void* g, void* l) {
  __builtin_amdgcn_global_load_lds(
      (const __attribute__((address_space(1))) unsigned int*)(uintptr_t)g,
      (__attribute__((address_space(3))) unsigned int*)(uintptr_t)l, 16, 0, 0);
}

// ---------------- transpose f32 [R][C] -> bf16 [C][R] ----------------
__global__ __launch_bounds__(256) void transpose_f32_bf16(
    const float* __restrict__ in, u16* __restrict__ out, int R, int C) {
  __shared__ float t[32][33];
  const int bx = blockIdx.x * 32;   // col base (C)
  const int by = blockIdx.y * 32;   // row base (R)
  const int tx = threadIdx.x, ty = threadIdx.y;   // 32 x 8
#pragma unroll
  for (int i = 0; i < 32; i += 8)
    t[ty + i][tx] = in[(size_t)(by + ty + i) * C + bx + tx];
  __syncthreads();
#pragma unroll
  for (int i = 0; i < 32; i += 8)
    out[(size_t)(bx + ty + i) * R + by + tx] = f2bf(t[tx][ty + i]);
}

// ---------------- RoPE tables ----------------
__global__ __launch_bounds__(256) void rope_tables(float* __restrict__ cosT,
                                                   float* __restrict__ sinT) {
  int idx = blockIdx.x * 256 + threadIdx.x;   // 2048*64
  int i = idx & 63, s = idx >> 6;
  float inv = powf(10000.0f, -2.0f * (float)i / 128.0f);
  float ang = (float)s * inv;
  cosT[idx] = cosf(ang);
  sinT[idx] = sinf(ang);
}

// ---------------- RoPE in-place on QKV (Q: 16 heads, K: 4 heads) -------------
__global__ __launch_bounds__(256) void rope_apply(u16* __restrict__ QKV,
                                                  const float* __restrict__ cosT,
                                                  const float* __restrict__ sinT) {
  int idx = blockIdx.x * 256 + threadIdx.x;        // NROW*20*64
  int i = idx & 63;
  int h20 = (idx >> 6) % 20;
  int row = idx / (64 * 20);
  int s = row & (S_LEN - 1);
  int col = (h20 < 16) ? (h20 * 128) : (2048 + (h20 - 16) * 128);
  size_t base = (size_t)row * DQKV + col;
  float v1 = bf2f(QKV[base + i]);
  float v2 = bf2f(QKV[base + 64 + i]);
  float c = cosT[s * 64 + i], sn = sinT[s * 64 + i];
  QKV[base + i]      = f2bf(v1 * c - v2 * sn);
  QKV[base + 64 + i] = f2bf(v1 * sn + v2 * c);
}

// ---------------- RMSNorm: f32 [rows][2048] -> bf16 ----------------
__global__ __launch_bounds__(256) void rmsnorm_kernel(const float* __restrict__ x,
                                                      const float* __restrict__ g,
                                                      u16* __restrict__ out) {
  const int row = blockIdx.x, tid = threadIdx.x;
  const float* xr = x + (size_t)row * 2048;
  float4 a = ((const float4*)xr)[tid * 2];
  float4 b = ((const float4*)xr)[tid * 2 + 1];
  float ss = a.x*a.x + a.y*a.y + a.z*a.z + a.w*a.w
           + b.x*b.x + b.y*b.y + b.z*b.z + b.w*b.w;
#pragma unroll
  for (int m = 1; m < 64; m <<= 1) ss += __shfl_xor(ss, m, 64);
  __shared__ float red[4];
  if ((tid & 63) == 0) red[tid >> 6] = ss;
  __syncthreads();
  float tot = red[0] + red[1] + red[2] + red[3];
  float rms = rsqrtf(tot * (1.0f / 2048.0f) + 1e-5f);
  const int c = tid * 8;
  float v[8] = {a.x,a.y,a.z,a.w,b.x,b.y,b.z,b.w};
  u16 o[8];
#pragma unroll
  for (int j = 0; j < 8; j++) o[j] = f2bf(v[j] * rms * g[c + j]);
  *(uint4*)(out + (size_t)row * 2048 + c) = *(uint4*)o;
}

// ---------------- GEMM: C[M][N] = A[M][K](bf16) * Bt[N][K](bf16) -------------
// MODE 0: bf16 out (+optional f32 bias)
// MODE 1: f32 out = acc + bias? + res[row][col]
// MODE 2: bf16 out = silu(g=outb[row][col]) * (acc + bias)   (in-place on outb)
template <int MODE>
__global__ __launch_bounds__(256) void gemm_bt(
    const u16* __restrict__ A, const u16* __restrict__ Bt,
    int M, int N, int K,
    const float* __restrict__ bias, const float* __restrict__ res,
    u16* __restrict__ outb, float* __restrict__ outf) {
  __shared__ u16 aLds[128 * 32] __attribute__((aligned(16)));
  __shared__ u16 bLds[128 * 32] __attribute__((aligned(16)));
  const int tid = threadIdx.x;
  const int m0 = blockIdx.y * 128, n0 = blockIdx.x * 128;
  const int l = tid & 63, w = tid >> 6;
  const int wr = (w >> 1) * 64, wc = (w & 1) * 64;
  const int lr = l & 15, lg = l >> 4;

  f32x4 acc[4][4] = {};

  const int o1 = tid * 16;          // bytes
  const int o2 = 4096 + tid * 16;
  const int r1 = o1 >> 6, c1 = o1 & 63;
  const int r2 = o2 >> 6, c2 = o2 & 63;

  for (int k0 = 0; k0 < K; k0 += 32) {
    __syncthreads();
    async16((const char*)A  + ((size_t)(m0 + r1) * K + k0) * 2 + c1, (char*)aLds + o1);
    async16((const char*)A  + ((size_t)(m0 + r2) * K + k0) * 2 + c2, (char*)aLds + o2);
    async16((const char*)Bt + ((size_t)(n0 + r1) * K + k0) * 2 + c1, (char*)bLds + o1);
    async16((const char*)Bt + ((size_t)(n0 + r2) * K + k0) * 2 + c2, (char*)bLds + o2);
    __syncthreads();
    bf16x8 aF[4], bF[4];
#pragma unroll
    for (int m = 0; m < 4; m++)
      aF[m] = *(const bf16x8*)&aLds[(wr + m * 16 + lr) * 32 + lg * 8];
#pragma unroll
    for (int n = 0; n < 4; n++)
      bF[n] = *(const bf16x8*)&bLds[(wc + n * 16 + lr) * 32 + lg * 8];
#pragma unroll
    for (int m = 0; m < 4; m++)
#pragma unroll
      for (int n = 0; n < 4; n++)
        acc[m][n] = __builtin_amdgcn_mfma_f32_16x16x32_bf16(aF[m], bF[n], acc[m][n], 0, 0, 0);
  }

#pragma unroll
  for (int m = 0; m < 4; m++) {
#pragma unroll
    for (int n = 0; n < 4; n++) {
      const int col = n0 + wc + n * 16 + lr;
      float bv = bias ? bias[col] : 0.0f;
#pragma unroll
      for (int r = 0; r < 4; r++) {
        const int row = m0 + wr + m * 16 + lg * 4 + r;
        const size_t idx = (size_t)row * N + col;
        float v = acc[m][n][r] + bv;
        if (MODE == 0) {
          outb[idx] = f2bf(v);
        } else if (MODE == 1) {
          outf[idx] = v + res[idx];
        } else {
          float gv = bf2f(outb[idx]);
          float sg = gv / (1.0f + __expf(-gv));
          outb[idx] = f2bf(sg * v);
        }
      }
    }
  }
}

// ---------------- Flash attention (causal, GQA kv = hq%4) ----------------
// grid: (S/128, B*16). 4 waves; wave w owns q rows [q0+w*32, +32).
__global__ __launch_bounds__(256) void attn_kernel(const u16* __restrict__ QKV,
                                                   u16* __restrict__ O) {
  const int bh = blockIdx.y;
  const int b = bh >> 4, hq = bh & 15;
  const int g = hq & 3;
  const int q0 = blockIdx.x * 128;
  const int tid = threadIdx.x, l = tid & 63, w = tid >> 6;
  const int lr = l & 15, lg = l >> 4;

  __shared__ u16 kT[32][136] __attribute__((aligned(16)));
  __shared__ u16 vT[128][40] __attribute__((aligned(16)));
  __shared__ u16 pT[4][32][40] __attribute__((aligned(16)));

  const float scale = 0.08838834764831845f;   // 1/sqrt(128)

  // Q fragments in registers (A-layout), pre-scaled domain kept raw
  bf16x8 qF[2][4];
  const int qrow_base = b * S_LEN + q0 + w * 32;
#pragma unroll
  for (int mq = 0; mq < 2; mq++)
#pragma unroll
    for (int kk = 0; kk < 4; kk++)
      qF[mq][kk] = *(const bf16x8*)(QKV + (size_t)(qrow_base + mq * 16 + lr) * DQKV
                                    + hq * 128 + kk * 32 + lg * 8);

  f32x4 o_acc[2][8] = {};
  float m_run[2][4], l_run[2][4];
#pragma unroll
  for (int mq = 0; mq < 2; mq++)
#pragma unroll
    for (int r = 0; r < 4; r++) { m_run[mq][r] = -1e30f; l_run[mq][r] = 0.0f; }

  const int myqmax = q0 + w * 32 + 31;
  const int nt = (q0 + 128) >> 5;

  for (int it = 0; it < nt; ++it) {
    const int t0 = it * 32;
    __syncthreads();
    {  // stage K tile [32][128] and V^T tile [128][32]
      const int r = tid >> 3;
      const int c = (tid & 7) * 16;
      const u16* ks = QKV + (size_t)(b * S_LEN + t0 + r) * DQKV + 2048 + g * 128 + c;
      bf16x8 k0v = *(const bf16x8*)ks;
      bf16x8 k1v = *(const bf16x8*)(ks + 8);
      *(bf16x8*)&kT[r][c] = k0v;
      *(bf16x8*)&kT[r][c + 8] = k1v;
      const u16* vs = QKV + (size_t)(b * S_LEN + t0 + r) * DQKV + 2560 + g * 128 + c;
      bf16x8 v0v = *(const bf16x8*)vs;
      bf16x8 v1v = *(const bf16x8*)(vs + 8);
#pragma unroll
      for (int j = 0; j < 8; j++) vT[c + j][r] = (u16)v0v[j];
#pragma unroll
      for (int j = 0; j < 8; j++) vT[c + 8 + j][r] = (u16)v1v[j];
    }
    __syncthreads();

    if (t0 <= myqmax) {
      // scores S = Q K^T (C layout: row=q=(lg*4+r), col=t=lr)
      f32x4 sc[2][2] = {};
#pragma unroll
      for (int mt = 0; mt < 2; mt++)
#pragma unroll
        for (int kk = 0; kk < 4; kk++) {
          bf16x8 kF = *(const bf16x8*)&kT[mt * 16 + lr][kk * 32 + lg * 8];
#pragma unroll
          for (int mq = 0; mq < 2; mq++)
            sc[mq][mt] = __builtin_amdgcn_mfma_f32_16x16x32_bf16(qF[mq][kk], kF, sc[mq][mt], 0, 0, 0);
        }
      const int qbase = q0 + w * 32;
#pragma unroll
      for (int mq = 0; mq < 2; mq++)
#pragma unroll
        for (int mt = 0; mt < 2; mt++)
#pragma unroll
          for (int r = 0; r < 4; r++) {
            float v = sc[mq][mt][r] * scale;
            int qg = qbase + mq * 16 + lg * 4 + r;
            int tg = t0 + mt * 16 + lr;
            sc[mq][mt][r] = (tg > qg) ? -1e30f : v;
          }
      // online softmax per (mq, r)
#pragma unroll
      for (int mq = 0; mq < 2; mq++) {
        float al[4];
#pragma unroll
        for (int r = 0; r < 4; r++) {
          float tmax = fmaxf(sc[mq][0][r], sc[mq][1][r]);
#pragma unroll
          for (int m = 1; m < 16; m <<= 1) tmax = fmaxf(tmax, __shfl_xor(tmax, m, 64));
          float mn = fmaxf(m_run[mq][r], tmax);
          float a = __expf(m_run[mq][r] - mn);
          m_run[mq][r] = mn;
          float p0 = __expf(sc[mq][0][r] - mn);
          float p1 = __expf(sc[mq][1][r] - mn);
          sc[mq][0][r] = p0; sc[mq][1][r] = p1;
          float rs = p0 + p1;
#pragma unroll
          for (int m = 1; m < 16; m <<= 1) rs += __shfl_xor(rs, m, 64);
          l_run[mq][r] = l_run[mq][r] * a + rs;
          al[r] = a;
        }
#pragma unroll
        for (int n = 0; n < 8; n++)
#pragma unroll
          for (int r = 0; r < 4; r++) o_acc[mq][n][r] *= al[r];
#pragma unroll
        for (int mt = 0; mt < 2; mt++)
#pragma unroll
          for (int r = 0; r < 4; r++)
            pT[w][mq * 16 + lg * 4 + r][mt * 16 + lr] = f2bf(sc[mq][mt][r]);
      }
      // PV: o += P[32q x 32t] * V[32t x 128d]
      bf16x8 pF0 = *(const bf16x8*)&pT[w][lr][lg * 8];
      bf16x8 pF1 = *(const bf16x8*)&pT[w][16 + lr][lg * 8];
#pragma unroll
      for (int n = 0; n < 8; n++) {
        bf16x8 vF = *(const bf16x8*)&vT[n * 16 + lr][lg * 8];
        o_acc[0][n] = __builtin_amdgcn_mfma_f32_16x16x32_bf16(pF0, vF, o_acc[0][n], 0, 0, 0);
        o_acc[1][n] = __builtin_amdgcn_mfma_f32_16x16x32_bf16(pF1, vF, o_acc[1][n], 0, 0, 0);
      }
    }
  }
  // epilogue
#pragma unroll
  for (int mq = 0; mq < 2; mq++)
#pragma unroll
    for (int n = 0; n < 8; n++)
#pragma unroll
      for (int r = 0; r < 4; r++) {
        float v = o_acc[mq][n][r] / l_run[mq][r];
        int row = b * S_LEN + q0 + w * 32 + mq * 16 + lg * 4 + r;
        int col = hq * 128 + n * 16 + lr;
        O[(size_t)row * 2048 + col] = f2bf(v);
      }
}

// ---------------- launch ----------------
extern "C" void kernel_launch(void* const* d_in, const int* in_sizes, int n_in,
                              void* d_out, int out_size, void* d_ws, size_t ws_size,
                              hipStream_t stream) {
  const float* x  = (const float*)d_in[0];
  const float* Wq = (const float*)d_in[2];
  const float* Wk = (const float*)d_in[3];
  const float* Wv = (const float*)d_in[4];
  const float* Wo = (const float*)d_in[5];
  const float* Wg = (const float*)d_in[6];
  const float* bg = (const float*)d_in[7];
  const float* Wu = (const float*)d_in[8];
  const float* bu = (const float*)d_in[9];
  const float* Wd = (const float*)d_in[10];
  const float* bd = (const float*)d_in[11];
  const float* g1 = (const float*)d_in[12];
  const float* g2 = (const float*)d_in[13];

  char* p = (char*)d_ws;
  auto alloc = [&](size_t bytes) { char* r = p; p += (bytes + 255) & ~(size_t)255; return r; };
  u16*   BtQKV = (u16*)alloc((size_t)DQKV * 2048 * 2);
  u16*   WoT   = (u16*)alloc((size_t)2048 * 2048 * 2);
  u16*   WgT   = (u16*)alloc((size_t)8192 * 2048 * 2);
  u16*   WuT   = (u16*)alloc((size_t)8192 * 2048 * 2);
  u16*   WdT   = (u16*)alloc((size_t)2048 * 8192 * 2);
  u16*   xn    = (u16*)alloc((size_t)NROW * 2048 * 2);   // also hn
  u16*   QKV   = (u16*)alloc((size_t)NROW * DQKV * 2);
  u16*   Obuf  = (u16*)alloc((size_t)NROW * 2048 * 2);
  float* h     = (float*)alloc((size_t)NROW * 2048 * 4);
  u16*   gact  = (u16*)alloc((size_t)NROW * 8192 * 2);
  float* cosT  = (float*)alloc((size_t)S_LEN * 64 * 4);
  float* sinT  = (float*)alloc((size_t)S_LEN * 64 * 4);

  dim3 tb(32, 8);
  transpose_f32_bf16<<<dim3(2048/32, 2048/32), tb, 0, stream>>>(Wq, BtQKV,                    2048, 2048);
  transpose_f32_bf16<<<dim3( 512/32, 2048/32), tb, 0, stream>>>(Wk, BtQKV + 2048ull*2048,     2048,  512);
  transpose_f32_bf16<<<dim3( 512/32, 2048/32), tb, 0, stream>>>(Wv, BtQKV + 2560ull*2048,     2048,  512);
  transpose_f32_bf16<<<dim3(2048/32, 2048/32), tb, 0, stream>>>(Wo, WoT,                      2048, 2048);
  transpose_f32_bf16<<<dim3(8192/32, 2048/32), tb, 0, stream>>>(Wg, WgT,                      2048, 8192);
  transpose_f32_bf16<<<dim3(8192/32, 2048/32), tb, 0, stream>>>(Wu, WuT,                      2048, 8192);
  transpose_f32_bf16<<<dim3(2048/32, 8192/32), tb, 0, stream>>>(Wd, WdT,                      8192, 2048);

  rope_tables<<<(S_LEN * 64) / 256, 256, 0, stream>>>(cosT, sinT);

  rmsnorm_kernel<<<NROW, 256, 0, stream>>>(x, g1, xn);

  gemm_bt<0><<<dim3(DQKV/128, NROW/128), 256, 0, stream>>>(xn, BtQKV, NROW, DQKV, 2048,
                                                           nullptr, nullptr, QKV, nullptr);

  rope_apply<<<(NROW * 20 * 64) / 256, 256, 0, stream>>>(QKV, cosT, sinT);

  attn_kernel<<<dim3(S_LEN/128, 32), 256, 0, stream>>>(QKV, Obuf);

  gemm_bt<1><<<dim3(2048/128, NROW/128), 256, 0, stream>>>(Obuf, WoT, NROW, 2048, 2048,
                                                           nullptr, x, nullptr, h);

  rmsnorm_kernel<<<NROW, 256, 0, stream>>>(h, g2, xn);

  gemm_bt<0><<<dim3(8192/128, NROW/128), 256, 0, stream>>>(xn, WgT, NROW, 8192, 2048,
                                                           bg, nullptr, gact, nullptr);
  gemm_bt<2><<<dim3(8192/128, NROW/128), 256, 0, stream>>>(xn, WuT, NROW, 8192, 2048,
                                                           bu, nullptr, gact, nullptr);
  gemm_bt<1><<<dim3(2048/128, NROW/128), 256, 0, stream>>>(gact, WdT, NROW, 2048, 8192,
                                                           bd, h, nullptr, (float*)d_out);
}

// Round 2
// 1093.629 us; speedup vs baseline: 1.0657x; 1.0657x over previous
//
#include <hip/hip_runtime.h>
#include <hip/hip_bf16.h>
#include <stdint.h>

#define S_LEN 2048
#define NROW  4096            // B*S
#define DQKV  3072            // 2048 Q + 512 K + 512 V

typedef unsigned short u16;
typedef __attribute__((ext_vector_type(8))) short bf16x8;
typedef __attribute__((ext_vector_type(4))) float f32x4;

__device__ __forceinline__ float bf2f(u16 v) {
  unsigned int u = ((unsigned int)v) << 16;
  return __builtin_bit_cast(float, u);
}
__device__ __forceinline__ u16 f2bf(float f) {
  unsigned int u = __builtin_bit_cast(unsigned int, f);
  u += 0x7FFFu + ((u >> 16) & 1u);
  return (u16)(u >> 16);
}
__device__ __forceinline__ void async16(const void* g, void* l) {
  __builtin_amdgcn_global_load_lds(
      (const __attribute__((address_space(1))) unsigned int*)(uintptr_t)g,
      (__attribute__((address_space(3))) unsigned int*)(uintptr_t)l, 16, 0, 0);
}

// ---------------- transpose f32 [R][C] -> bf16 [C][R] ----------------
__global__ __launch_bounds__(256) void transpose_f32_bf16(
    const float* __restrict__ in, u16* __restrict__ out, int R, int C) {
  __shared__ float t[32][33];
  const int bx = blockIdx.x * 32;   // col base (C)
  const int by = blockIdx.y * 32;   // row base (R)
  const int tx = threadIdx.x, ty = threadIdx.y;   // 32 x 8
#pragma unroll
  for (int i = 0; i < 32; i += 8)
    t[ty + i][tx] = in[(size_t)(by + ty + i) * C + bx + tx];
  __syncthreads();
#pragma unroll
  for (int i = 0; i < 32; i += 8)
    out[(size_t)(bx + ty + i) * R + by + tx] = f2bf(t[tx][ty + i]);
}

// ---------------- RoPE tables ----------------
__global__ __launch_bounds__(256) void rope_tables(float* __restrict__ cosT,
                                                   float* __restrict__ sinT) {
  int idx = blockIdx.x * 256 + threadIdx.x;   // 2048*64
  int i = idx & 63, s = idx >> 6;
  float inv = powf(10000.0f, -2.0f * (float)i / 128.0f);
  float ang = (float)s * inv;
  cosT[idx] = cosf(ang);
  sinT[idx] = sinf(ang);
}

// ---------------- RoPE in-place on QKV (Q: 16 heads, K: 4 heads) -------------
__global__ __launch_bounds__(256) void rope_apply(u16* __restrict__ QKV,
                                                  const float* __restrict__ cosT,
                                                  const float* __restrict__ sinT) {
  int idx = blockIdx.x * 256 + threadIdx.x;        // NROW*20*64
  int i = idx & 63;
  int h20 = (idx >> 6) % 20;
  int row = idx / (64 * 20);
  int s = row & (S_LEN - 1);
  int col = (h20 < 16) ? (h20 * 128) : (2048 + (h20 - 16) * 128);
  size_t base = (size_t)row * DQKV + col;
  float v1 = bf2f(QKV[base + i]);
  float v2 = bf2f(QKV[base + 64 + i]);
  float c = cosT[s * 64 + i], sn = sinT[s * 64 + i];
  QKV[base + i]      = f2bf(v1 * c - v2 * sn);
  QKV[base + 64 + i] = f2bf(v1 * sn + v2 * c);
}

// ---------------- RMSNorm: f32 [rows][2048] -> bf16 ----------------
__global__ __launch_bounds__(256) void rmsnorm_kernel(const float* __restrict__ x,
                                                      const float* __restrict__ g,
                                                      u16* __restrict__ out) {
  const int row = blockIdx.x, tid = threadIdx.x;
  const float* xr = x + (size_t)row * 2048;
  float4 a = ((const float4*)xr)[tid * 2];
  float4 b = ((const float4*)xr)[tid * 2 + 1];
  float ss = a.x*a.x + a.y*a.y + a.z*a.z + a.w*a.w
           + b.x*b.x + b.y*b.y + b.z*b.z + b.w*b.w;
#pragma unroll
  for (int m = 1; m < 64; m <<= 1) ss += __shfl_xor(ss, m, 64);
  __shared__ float red[4];
  if ((tid & 63) == 0) red[tid >> 6] = ss;
  __syncthreads();
  float tot = red[0] + red[1] + red[2] + red[3];
  float rms = rsqrtf(tot * (1.0f / 2048.0f) + 1e-5f);
  const int c = tid * 8;
  float v[8] = {a.x,a.y,a.z,a.w,b.x,b.y,b.z,b.w};
  u16 o[8];
#pragma unroll
  for (int j = 0; j < 8; j++) o[j] = f2bf(v[j] * rms * g[c + j]);
  *(uint4*)(out + (size_t)row * 2048 + c) = *(uint4*)o;
}

// ---------------- GEMM: C[M][N] = A[M][K](bf16) * Bt[N][K](bf16) -------------
// MODE 0: bf16 out (+optional f32 bias)
// MODE 1: f32 out = acc + bias? + res[row][col]
// MODE 2: bf16 out = silu(g=outb[row][col]) * (acc + bias)   (in-place on outb)
template <int MODE>
__global__ __launch_bounds__(256) void gemm_bt(
    const u16* __restrict__ A, const u16* __restrict__ Bt,
    int M, int N, int K,
    const float* __restrict__ bias, const float* __restrict__ res,
    u16* __restrict__ outb, float* __restrict__ outf) {
  __shared__ u16 aLds[128 * 32] __attribute__((aligned(16)));
  __shared__ u16 bLds[128 * 32] __attribute__((aligned(16)));
  const int tid = threadIdx.x;
  // XCD-aware bijective swizzle (grids here are all %8 == 0)
  const int nwg = gridDim.x * gridDim.y;
  int wg = blockIdx.y * gridDim.x + blockIdx.x;
  wg = (wg & 7) * (nwg >> 3) + (wg >> 3);
  const int m0 = (wg / gridDim.x) * 128, n0 = (wg % gridDim.x) * 128;
  const int l = tid & 63, w = tid >> 6;
  const int wr = (w >> 1) * 64, wc = (w & 1) * 64;
  const int lr = l & 15, lg = l >> 4;

  f32x4 acc[4][4] = {};

  const int o1 = tid * 16;          // bytes
  const int o2 = 4096 + tid * 16;
  const int r1 = o1 >> 6, c1 = o1 & 63;
  const int r2 = o2 >> 6, c2 = o2 & 63;

  for (int k0 = 0; k0 < K; k0 += 32) {
    __syncthreads();
    async16((const char*)A  + ((size_t)(m0 + r1) * K + k0) * 2 + c1, (char*)aLds + o1);
    async16((const char*)A  + ((size_t)(m0 + r2) * K + k0) * 2 + c2, (char*)aLds + o2);
    async16((const char*)Bt + ((size_t)(n0 + r1) * K + k0) * 2 + c1, (char*)bLds + o1);
    async16((const char*)Bt + ((size_t)(n0 + r2) * K + k0) * 2 + c2, (char*)bLds + o2);
    __syncthreads();
    bf16x8 aF[4], bF[4];
#pragma unroll
    for (int m = 0; m < 4; m++)
      aF[m] = *(const bf16x8*)&aLds[(wr + m * 16 + lr) * 32 + lg * 8];
#pragma unroll
    for (int n = 0; n < 4; n++)
      bF[n] = *(const bf16x8*)&bLds[(wc + n * 16 + lr) * 32 + lg * 8];
#pragma unroll
    for (int m = 0; m < 4; m++)
#pragma unroll
      for (int n = 0; n < 4; n++)
        acc[m][n] = __builtin_amdgcn_mfma_f32_16x16x32_bf16(aF[m], bF[n], acc[m][n], 0, 0, 0);
  }

#pragma unroll
  for (int m = 0; m < 4; m++) {
#pragma unroll
    for (int n = 0; n < 4; n++) {
      const int col = n0 + wc + n * 16 + lr;
      float bv = bias ? bias[col] : 0.0f;
#pragma unroll
      for (int r = 0; r < 4; r++) {
        const int row = m0 + wr + m * 16 + lg * 4 + r;
        const size_t idx = (size_t)row * N + col;
        float v = acc[m][n][r] + bv;
        if (MODE == 0) {
          outb[idx] = f2bf(v);
        } else if (MODE == 1) {
          outf[idx] = v + res[idx];
        } else {
          float gv = bf2f(outb[idx]);
          float sg = gv / (1.0f + __expf(-gv));
          outb[idx] = f2bf(sg * v);
        }
      }
    }
  }
}

// ---------------- Flash attention (causal, GQA kv = hq%4) ----------------
// 512 blocks, 4 waves each; wave w owns 32 q rows. KVBLK=64.
// Balance: block k and k+256 (same CU) get complementary qtiles.
__global__ __launch_bounds__(256) void attn_kernel(const u16* __restrict__ QKV,
                                                   u16* __restrict__ O) {
  const int bid = blockIdx.x;
  const int half = bid >> 8, rr = bid & 255;
  const int bh = rr >> 3, tt = rr & 7;
  const int qtile = half ? (15 - tt) : tt;
  const int b = bh >> 4, hq = bh & 15, g = hq & 3;
  const int q0 = qtile * 128;
  const int tid = threadIdx.x, l = tid & 63, w = tid >> 6;
  const int lr = l & 15, lg = l >> 4;

  __shared__ u16 kT[64 * 128] __attribute__((aligned(16)));   // [t][d], d-chunk ^= (t&7)
  __shared__ u16 vT[128 * 64] __attribute__((aligned(16)));   // [d][t], t-chunk ^= (d^(d>>4))&7
  __shared__ u16 pT[4][32 * 72] __attribute__((aligned(16)));

  const float scale = 0.08838834764831845f;   // 1/sqrt(128)

  // Q fragments in registers (A-layout)
  bf16x8 qF[2][4];
  const int qrow_base = b * S_LEN + q0 + w * 32;
#pragma unroll
  for (int mq = 0; mq < 2; mq++)
#pragma unroll
    for (int kk = 0; kk < 4; kk++)
      qF[mq][kk] = *(const bf16x8*)(QKV + (size_t)(qrow_base + mq * 16 + lr) * DQKV
                                    + hq * 128 + kk * 32 + lg * 8);

  f32x4 o_acc[2][8] = {};
  float m_run[2][4], l_run[2][4];
#pragma unroll
  for (int mq = 0; mq < 2; mq++)
#pragma unroll
    for (int r = 0; r < 4; r++) { m_run[mq][r] = -1e30f; l_run[mq][r] = 0.0f; }

  const int qmin_w = q0 + w * 32;
  const int nt = (q0 + 128) >> 6;

  for (int it = 0; it < nt; ++it) {
    const int t0 = it * 64;
    __syncthreads();
    {  // stage K [64][128] (swizzled) and V^T [128][64] (swizzled), 2 passes
      const int rbase = tid >> 3;          // 0..31
      const int c16 = (tid & 7) * 16;      // 0..112
#pragma unroll
      for (int pass = 0; pass < 2; ++pass) {
        const int r = rbase + pass * 32;
        const u16* src = QKV + (size_t)(b * S_LEN + t0 + r) * DQKV + 2048 + g * 128 + c16;
        const int rk = r & 7;
#pragma unroll
        for (int jj = 0; jj < 2; ++jj) {
          bf16x8 kv = *(const bf16x8*)(src + jj * 8);
          const int chunk = (c16 >> 3) + jj;
          *(bf16x8*)&kT[r * 128 + ((chunk ^ rk) << 3)] = kv;
        }
#pragma unroll
        for (int jj = 0; jj < 2; ++jj) {
          bf16x8 vv = *(const bf16x8*)(src + 512 + jj * 8);
#pragma unroll
          for (int j = 0; j < 8; ++j) {
            const int d = c16 + jj * 8 + j;
            const int key = (d ^ (d >> 4)) & 7;
            vT[d * 64 + (r & 7) + (((r >> 3) ^ key) << 3)] = (u16)vv[j];
          }
        }
      }
    }
    __syncthreads();

    if (t0 <= qmin_w + 31) {
      // scores S = Q K^T : C layout row=q (lg*4+r), col=t (lr)
      f32x4 sc[2][4] = {};
#pragma unroll
      for (int mt = 0; mt < 4; mt++) {
        const int t = mt * 16 + lr;
        const int tk = t & 7;
#pragma unroll
        for (int kk = 0; kk < 4; kk++) {
          bf16x8 kF = *(const bf16x8*)&kT[t * 128 + (((kk * 4 + lg) ^ tk) << 3)];
          sc[0][mt] = __builtin_amdgcn_mfma_f32_16x16x32_bf16(qF[0][kk], kF, sc[0][mt], 0, 0, 0);
          sc[1][mt] = __builtin_amdgcn_mfma_f32_16x16x32_bf16(qF[1][kk], kF, sc[1][mt], 0, 0, 0);
        }
      }
      const bool needMask = (t0 + 63 > qmin_w);
#pragma unroll
      for (int mq = 0; mq < 2; mq++)
#pragma unroll
        for (int mt = 0; mt < 4; mt++)
#pragma unroll
          for (int r = 0; r < 4; r++) {
            float v = sc[mq][mt][r] * scale;
            if (needMask) {
              int qg = qmin_w + mq * 16 + lg * 4 + r;
              int tg = t0 + mt * 16 + lr;
              if (tg > qg) v = -1e30f;
            }
            sc[mq][mt][r] = v;
          }
      // online softmax per (mq, r)
#pragma unroll
      for (int mq = 0; mq < 2; mq++) {
        float al[4];
#pragma unroll
        for (int r = 0; r < 4; r++) {
          float tmax = fmaxf(fmaxf(sc[mq][0][r], sc[mq][1][r]),
                             fmaxf(sc[mq][2][r], sc[mq][3][r]));
#pragma unroll
          for (int m = 1; m < 16; m <<= 1) tmax = fmaxf(tmax, __shfl_xor(tmax, m, 64));
          float mn = fmaxf(m_run[mq][r], tmax);
          float a = __expf(m_run[mq][r] - mn);
          m_run[mq][r] = mn;
          float rs = 0.0f;
#pragma unroll
          for (int mt = 0; mt < 4; mt++) {
            float pv = __expf(sc[mq][mt][r] - mn);
            sc[mq][mt][r] = pv;
            rs += pv;
          }
#pragma unroll
          for (int m = 1; m < 16; m <<= 1) rs += __shfl_xor(rs, m, 64);
          l_run[mq][r] = l_run[mq][r] * a + rs;
          al[r] = a;
        }
#pragma unroll
        for (int n = 0; n < 8; n++)
#pragma unroll
          for (int r = 0; r < 4; r++) o_acc[mq][n][r] *= al[r];
#pragma unroll
        for (int mt = 0; mt < 4; mt++)
#pragma unroll
          for (int r = 0; r < 4; r++)
            pT[w][(mq * 16 + lg * 4 + r) * 72 + mt * 16 + lr] = f2bf(sc[mq][mt][r]);
      }
      // PV: o += P[32q x 64t] * V[64t x 128d]
      bf16x8 pF[2][2];
#pragma unroll
      for (int mq = 0; mq < 2; mq++)
#pragma unroll
        for (int kt = 0; kt < 2; kt++)
          pF[mq][kt] = *(const bf16x8*)&pT[w][(mq * 16 + lr) * 72 + kt * 32 + lg * 8];
#pragma unroll
      for (int kt = 0; kt < 2; kt++)
#pragma unroll
        for (int n = 0; n < 8; n++) {
          const int d = n * 16 + lr;
          const int key = (d ^ (d >> 4)) & 7;
          bf16x8 vF = *(const bf16x8*)&vT[d * 64 + (((kt * 4 + lg) ^ key) << 3)];
          o_acc[0][n] = __builtin_amdgcn_mfma_f32_16x16x32_bf16(pF[0][kt], vF, o_acc[0][n], 0, 0, 0);
          o_acc[1][n] = __builtin_amdgcn_mfma_f32_16x16x32_bf16(pF[1][kt], vF, o_acc[1][n], 0, 0, 0);
        }
    }
  }
  // epilogue
#pragma unroll
  for (int mq = 0; mq < 2; mq++)
#pragma unroll
    for (int n = 0; n < 8; n++)
#pragma unroll
      for (int r = 0; r < 4; r++) {
        float v = o_acc[mq][n][r] / l_run[mq][r];
        int row = b * S_LEN + q0 + w * 32 + mq * 16 + lg * 4 + r;
        int col = hq * 128 + n * 16 + lr;
        O[(size_t)row * 2048 + col] = f2bf(v);
      }
}

// ---------------- launch ----------------
extern "C" void kernel_launch(void* const* d_in, const int* in_sizes, int n_in,
                              void* d_out, int out_size, void* d_ws, size_t ws_size,
                              hipStream_t stream) {
  const float* x  = (const float*)d_in[0];
  const float* Wq = (const float*)d_in[2];
  const float* Wk = (const float*)d_in[3];
  const float* Wv = (const float*)d_in[4];
  const float* Wo = (const float*)d_in[5];
  const float* Wg = (const float*)d_in[6];
  const float* bg = (const float*)d_in[7];
  const float* Wu = (const float*)d_in[8];
  const float* bu = (const float*)d_in[9];
  const float* Wd = (const float*)d_in[10];
  const float* bd = (const float*)d_in[11];
  const float* g1 = (const float*)d_in[12];
  const float* g2 = (const float*)d_in[13];

  char* p = (char*)d_ws;
  auto alloc = [&](size_t bytes) { char* r = p; p += (bytes + 255) & ~(size_t)255; return r; };
  u16*   BtQKV = (u16*)alloc((size_t)DQKV * 2048 * 2);
  u16*   WoT   = (u16*)alloc((size_t)2048 * 2048 * 2);
  u16*   WgT   = (u16*)alloc((size_t)8192 * 2048 * 2);
  u16*   WuT   = (u16*)alloc((size_t)8192 * 2048 * 2);
  u16*   WdT   = (u16*)alloc((size_t)2048 * 8192 * 2);
  u16*   xn    = (u16*)alloc((size_t)NROW * 2048 * 2);   // also hn
  u16*   QKV   = (u16*)alloc((size_t)NROW * DQKV * 2);
  u16*   Obuf  = (u16*)alloc((size_t)NROW * 2048 * 2);
  float* h     = (float*)alloc((size_t)NROW * 2048 * 4);
  u16*   gact  = (u16*)alloc((size_t)NROW * 8192 * 2);
  float* cosT  = (float*)alloc((size_t)S_LEN * 64 * 4);
  float* sinT  = (float*)alloc((size_t)S_LEN * 64 * 4);

  dim3 tb(32, 8);
  transpose_f32_bf16<<<dim3(2048/32, 2048/32), tb, 0, stream>>>(Wq, BtQKV,                    2048, 2048);
  transpose_f32_bf16<<<dim3( 512/32, 2048/32), tb, 0, stream>>>(Wk, BtQKV + 2048ull*2048,     2048,  512);
  transpose_f32_bf16<<<dim3( 512/32, 2048/32), tb, 0, stream>>>(Wv, BtQKV + 2560ull*2048,     2048,  512);
  transpose_f32_bf16<<<dim3(2048/32, 2048/32), tb, 0, stream>>>(Wo, WoT,                      2048, 2048);
  transpose_f32_bf16<<<dim3(8192/32, 2048/32), tb, 0, stream>>>(Wg, WgT,                      2048, 8192);
  transpose_f32_bf16<<<dim3(8192/32, 2048/32), tb, 0, stream>>>(Wu, WuT,                      2048, 8192);
  transpose_f32_bf16<<<dim3(2048/32, 8192/32), tb, 0, stream>>>(Wd, WdT,                      8192, 2048);

  rope_tables<<<(S_LEN * 64) / 256, 256, 0, stream>>>(cosT, sinT);

  rmsnorm_kernel<<<NROW, 256, 0, stream>>>(x, g1, xn);

  gemm_bt<0><<<dim3(DQKV/128, NROW/128), 256, 0, stream>>>(xn, BtQKV, NROW, DQKV, 2048,
                                                           nullptr, nullptr, QKV, nullptr);

  rope_apply<<<(NROW * 20 * 64) / 256, 256, 0, stream>>>(QKV, cosT, sinT);

  attn_kernel<<<512, 256, 0, stream>>>(QKV, Obuf);

  gemm_bt<1><<<dim3(2048/128, NROW/128), 256, 0, stream>>>(Obuf, WoT, NROW, 2048, 2048,
                                                           nullptr, x, nullptr, h);

  rmsnorm_kernel<<<NROW, 256, 0, stream>>>(h, g2, xn);

  gemm_bt<0><<<dim3(8192/128, NROW/128), 256, 0, stream>>>(xn, WgT, NROW, 8192, 2048,
                                                           bg, nullptr, gact, nullptr);
  gemm_bt<2><<<dim3(8192/128, NROW/128), 256, 0, stream>>>(xn, WuT, NROW, 8192, 2048,
                                                           bu, nullptr, gact, nullptr);
  gemm_bt<1><<<dim3(2048/128, NROW/128), 256, 0, stream>>>(gact, WdT, NROW, 2048, 8192,
                                                           bd, h, nullptr, (float*)d_out);
}

// Round 3
// 829.041 us; speedup vs baseline: 1.4058x; 1.3192x over previous
//
#include <hip/hip_runtime.h>
#include <hip/hip_bf16.h>
#include <stdint.h>

#define S_LEN 2048
#define NROW  4096            // B*S
#define DQKV  3072            // 2048 Q + 512 K + 512 V

typedef unsigned short u16;
typedef __attribute__((ext_vector_type(8))) short bf16x8;
typedef __attribute__((ext_vector_type(4))) float f32x4;

__device__ __forceinline__ float bf2f(u16 v) {
  unsigned int u = ((unsigned int)v) << 16;
  return __builtin_bit_cast(float, u);
}
__device__ __forceinline__ u16 f2bf(float f) {
  unsigned int u = __builtin_bit_cast(unsigned int, f);
  u += 0x7FFFu + ((u >> 16) & 1u);
  return (u16)(u >> 16);
}
__device__ __forceinline__ void async16(const void* g, void* l) {
  __builtin_amdgcn_global_load_lds(
      (const __attribute__((address_space(1))) unsigned int*)(uintptr_t)g,
      (__attribute__((address_space(3))) unsigned int*)(uintptr_t)l, 16, 0, 0);
}

// ---------------- transpose f32 [R][C] -> bf16 [C][R] ----------------
__global__ __launch_bounds__(256) void transpose_f32_bf16(
    const float* __restrict__ in, u16* __restrict__ out, int R, int C) {
  __shared__ float t[32][33];
  const int bx = blockIdx.x * 32;   // col base (C)
  const int by = blockIdx.y * 32;   // row base (R)
  const int tx = threadIdx.x, ty = threadIdx.y;   // 32 x 8
#pragma unroll
  for (int i = 0; i < 32; i += 8)
    t[ty + i][tx] = in[(size_t)(by + ty + i) * C + bx + tx];
  __syncthreads();
#pragma unroll
  for (int i = 0; i < 32; i += 8)
    out[(size_t)(bx + ty + i) * R + by + tx] = f2bf(t[tx][ty + i]);
}

// ---------------- RoPE tables ----------------
__global__ __launch_bounds__(256) void rope_tables(float* __restrict__ cosT,
                                                   float* __restrict__ sinT) {
  int idx = blockIdx.x * 256 + threadIdx.x;   // 2048*64
  int i = idx & 63, s = idx >> 6;
  float inv = powf(10000.0f, -2.0f * (float)i / 128.0f);
  float ang = (float)s * inv;
  cosT[idx] = cosf(ang);
  sinT[idx] = sinf(ang);
}

// ---------------- RoPE in-place on QKV (Q: 16 heads, K: 4 heads) -------------
__global__ __launch_bounds__(256) void rope_apply(u16* __restrict__ QKV,
                                                  const float* __restrict__ cosT,
                                                  const float* __restrict__ sinT) {
  int idx = blockIdx.x * 256 + threadIdx.x;        // NROW*20*64
  int i = idx & 63;
  int h20 = (idx >> 6) % 20;
  int row = idx / (64 * 20);
  int s = row & (S_LEN - 1);
  int col = (h20 < 16) ? (h20 * 128) : (2048 + (h20 - 16) * 128);
  size_t base = (size_t)row * DQKV + col;
  float v1 = bf2f(QKV[base + i]);
  float v2 = bf2f(QKV[base + 64 + i]);
  float c = cosT[s * 64 + i], sn = sinT[s * 64 + i];
  QKV[base + i]      = f2bf(v1 * c - v2 * sn);
  QKV[base + 64 + i] = f2bf(v1 * sn + v2 * c);
}

// ---------------- RMSNorm: f32 [rows][2048] -> bf16 ----------------
__global__ __launch_bounds__(256) void rmsnorm_kernel(const float* __restrict__ x,
                                                      const float* __restrict__ g,
                                                      u16* __restrict__ out) {
  const int row = blockIdx.x, tid = threadIdx.x;
  const float* xr = x + (size_t)row * 2048;
  float4 a = ((const float4*)xr)[tid * 2];
  float4 b = ((const float4*)xr)[tid * 2 + 1];
  float ss = a.x*a.x + a.y*a.y + a.z*a.z + a.w*a.w
           + b.x*b.x + b.y*b.y + b.z*b.z + b.w*b.w;
#pragma unroll
  for (int m = 1; m < 64; m <<= 1) ss += __shfl_xor(ss, m, 64);
  __shared__ float red[4];
  if ((tid & 63) == 0) red[tid >> 6] = ss;
  __syncthreads();
  float tot = red[0] + red[1] + red[2] + red[3];
  float rms = rsqrtf(tot * (1.0f / 2048.0f) + 1e-5f);
  const int c = tid * 8;
  float v[8] = {a.x,a.y,a.z,a.w,b.x,b.y,b.z,b.w};
  u16 o[8];
#pragma unroll
  for (int j = 0; j < 8; j++) o[j] = f2bf(v[j] * rms * g[c + j]);
  *(uint4*)(out + (size_t)row * 2048 + c) = *(uint4*)o;
}

// ============ 256-wide GEMM, 4-slot LDS ring, counted vmcnt ============
// C[M][N] = A[M][K](bf16) * Bt[N][K](bf16)
// MODE 0: bf16 out.  MODE 1: f32 out = acc + bias? + res.
// LDS slot layout (A and B): logical (row r, 16B k-chunk kc in 0..3) stored at
//   pairrow p = r>>1, chunk c' = (kc + 4*(r&1)) ^ (p&7), byte = p*128 + c'*16.
template <int BN, int MODE>
__global__ __launch_bounds__(512, 2) void gemm256(
    const u16* __restrict__ A, const u16* __restrict__ Bt,
    int nx, int K, int N,
    const float* __restrict__ bias, const float* __restrict__ res,
    u16* __restrict__ outb, float* __restrict__ outf) {
  constexpr int BSLOT = (BN == 256) ? 16384 : 8192;
  constexpr int NF = BN / 64;
  __shared__ char ldsA[4 * 16384] __attribute__((aligned(16)));
  __shared__ char ldsB[4 * BSLOT] __attribute__((aligned(16)));
  const int t = threadIdx.x;
  const int nwg = gridDim.x;
  const int wg = ((int)blockIdx.x & 7) * (nwg >> 3) + ((int)blockIdx.x >> 3);
  const int m0 = (wg / nx) * 256, n0 = (wg % nx) * BN;
  const int l = t & 63, w = t >> 6;
  const int wm = w >> 2, wn = w & 3;
  const int lr = l & 15, lg = l >> 4;

  // staging source mapping (inverse swizzle): thread t covers LDS bytes t*16
  const int cA  = (t & 7) ^ ((t >> 3) & 7);
  const int rb  = 2 * (t >> 3) + (cA >> 2);
  const int kcb = (cA & 3) * 16;
  const int t16 = t * 16;
  const char* aS0 = (const char*)A  + ((size_t)(m0 + rb) * K) * 2 + kcb;
  const char* aS1 = aS0 + (size_t)128 * K * 2;
  const char* bS0 = (const char*)Bt + ((size_t)(n0 + rb) * K) * 2 + kcb;
  const char* bS1 = bS0 + (size_t)128 * K * 2;

  const int NT = K >> 5;

  auto STAGE = [&](int kt) {
    const int slot = kt & 3;
    const size_t ko = (size_t)kt * 64;   // bytes along K
    char* sA = ldsA + slot * 16384;
    async16(aS0 + ko, sA + t16);
    async16(aS1 + ko, sA + 8192 + t16);
    char* sB = ldsB + slot * BSLOT;
    async16(bS0 + ko, sB + t16);
    if constexpr (BN == 256) async16(bS1 + ko, sB + 8192 + t16);
  };

  STAGE(0); STAGE(1); STAGE(2);

  f32x4 acc[8][NF] = {};
  const int ci  = ((lg + ((lr & 1) << 2)) ^ ((lr >> 1) & 7)) << 4;
  const int aRd = (wm * 64 + (lr >> 1)) * 128 + ci;
  const int bRd = ((BN == 256 ? wn * 32 : wn * 16) + (lr >> 1)) * 128 + ci;

  for (int kt = 0; kt < NT; ++kt) {
    if (kt < NT - 2) {
      if constexpr (BN == 256) asm volatile("s_waitcnt vmcnt(8)" ::: "memory");
      else                     asm volatile("s_waitcnt vmcnt(6)" ::: "memory");
    } else if (kt == NT - 2) {
      if constexpr (BN == 256) asm volatile("s_waitcnt vmcnt(4)" ::: "memory");
      else                     asm volatile("s_waitcnt vmcnt(3)" ::: "memory");
    } else {
      asm volatile("s_waitcnt vmcnt(0)" ::: "memory");
    }
    __builtin_amdgcn_sched_barrier(0);
    __builtin_amdgcn_s_barrier();
    __builtin_amdgcn_sched_barrier(0);
    if (kt + 3 < NT) STAGE(kt + 3);
    const char* sA = ldsA + (kt & 3) * 16384;
    const char* sB = ldsB + (kt & 3) * BSLOT;
    bf16x8 aF[8], bF[NF];
#pragma unroll
    for (int m = 0; m < 8; m++) aF[m] = *(const bf16x8*)(sA + aRd + m * 1024);
#pragma unroll
    for (int n = 0; n < NF; n++) bF[n] = *(const bf16x8*)(sB + bRd + n * 1024);
    __builtin_amdgcn_s_setprio(1);
#pragma unroll
    for (int m = 0; m < 8; m++)
#pragma unroll
      for (int n = 0; n < NF; n++)
        acc[m][n] = __builtin_amdgcn_mfma_f32_16x16x32_bf16(aF[m], bF[n], acc[m][n], 0, 0, 0);
    __builtin_amdgcn_s_setprio(0);
  }

#pragma unroll
  for (int m = 0; m < 8; m++) {
    const int row = m0 + wm * 128 + m * 16 + lg * 4;
#pragma unroll
    for (int n = 0; n < NF; n++) {
      const int col = n0 + wn * (BN / 4) + n * 16 + lr;
      const float bv = bias ? bias[col] : 0.0f;
#pragma unroll
      for (int r = 0; r < 4; r++) {
        const size_t idx = (size_t)(row + r) * N + col;
        float v = acc[m][n][r] + bv;
        if (MODE == 0) outb[idx] = f2bf(v);
        else           outf[idx] = v + res[idx];
      }
    }
  }
}

// ============ fused SwiGLU GEMM: out = silu(A*Wg^T + bg) * (A*Wu^T + bu) =====
// Block computes a 256x128 tile of BOTH g and u; B-tile = 128 rows Wg || 128 rows Wu.
__global__ __launch_bounds__(512, 2) void swiglu_gemm(
    const u16* __restrict__ A, const u16* __restrict__ Bg, const u16* __restrict__ Bu,
    int nx, int K, const float* __restrict__ bgv, const float* __restrict__ buv,
    u16* __restrict__ out) {
  __shared__ char ldsA[4 * 16384] __attribute__((aligned(16)));
  __shared__ char ldsB[4 * 16384] __attribute__((aligned(16)));
  const int t = threadIdx.x;
  const int nwg = gridDim.x;
  const int wg = ((int)blockIdx.x & 7) * (nwg >> 3) + ((int)blockIdx.x >> 3);
  const int m0 = (wg / nx) * 256, n0 = (wg % nx) * 128;
  const int l = t & 63, w = t >> 6;
  const int wm = w >> 2, wn = w & 3;
  const int lr = l & 15, lg = l >> 4;

  const int cA  = (t & 7) ^ ((t >> 3) & 7);
  const int rb  = 2 * (t >> 3) + (cA >> 2);
  const int kcb = (cA & 3) * 16;
  const int t16 = t * 16;
  const char* aS0 = (const char*)A  + ((size_t)(m0 + rb) * K) * 2 + kcb;
  const char* aS1 = aS0 + (size_t)128 * K * 2;
  const char* gS  = (const char*)Bg + ((size_t)(n0 + rb) * K) * 2 + kcb;
  const char* uS  = (const char*)Bu + ((size_t)(n0 + rb) * K) * 2 + kcb;

  const int NT = K >> 5;

  auto STAGE = [&](int kt) {
    const int slot = kt & 3;
    const size_t ko = (size_t)kt * 64;
    char* sA = ldsA + slot * 16384;
    async16(aS0 + ko, sA + t16);
    async16(aS1 + ko, sA + 8192 + t16);
    char* sB = ldsB + slot * 16384;
    async16(gS + ko, sB + t16);
    async16(uS + ko, sB + 8192 + t16);
  };

  STAGE(0); STAGE(1); STAGE(2);

  f32x4 accg[8][2] = {}, accu[8][2] = {};
  const int ci  = ((lg + ((lr & 1) << 2)) ^ ((lr >> 1) & 7)) << 4;
  const int aRd = (wm * 64 + (lr >> 1)) * 128 + ci;
  const int bRd = (wn * 16 + (lr >> 1)) * 128 + ci;

  for (int kt = 0; kt < NT; ++kt) {
    if (kt < NT - 2)       asm volatile("s_waitcnt vmcnt(8)" ::: "memory");
    else if (kt == NT - 2) asm volatile("s_waitcnt vmcnt(4)" ::: "memory");
    else                   asm volatile("s_waitcnt vmcnt(0)" ::: "memory");
    __builtin_amdgcn_sched_barrier(0);
    __builtin_amdgcn_s_barrier();
    __builtin_amdgcn_sched_barrier(0);
    if (kt + 3 < NT) STAGE(kt + 3);
    const char* sA = ldsA + (kt & 3) * 16384;
    const char* sB = ldsB + (kt & 3) * 16384;
    bf16x8 aF[8], gF[2], uF[2];
#pragma unroll
    for (int m = 0; m < 8; m++) aF[m] = *(const bf16x8*)(sA + aRd + m * 1024);
#pragma unroll
    for (int n = 0; n < 2; n++) {
      gF[n] = *(const bf16x8*)(sB + bRd + n * 1024);
      uF[n] = *(const bf16x8*)(sB + 8192 + bRd + n * 1024);
    }
    __builtin_amdgcn_s_setprio(1);
#pragma unroll
    for (int m = 0; m < 8; m++)
#pragma unroll
      for (int n = 0; n < 2; n++) {
        accg[m][n] = __builtin_amdgcn_mfma_f32_16x16x32_bf16(aF[m], gF[n], accg[m][n], 0, 0, 0);
        accu[m][n] = __builtin_amdgcn_mfma_f32_16x16x32_bf16(aF[m], uF[n], accu[m][n], 0, 0, 0);
      }
    __builtin_amdgcn_s_setprio(0);
  }

#pragma unroll
  for (int m = 0; m < 8; m++) {
    const int row = m0 + wm * 128 + m * 16 + lg * 4;
#pragma unroll
    for (int n = 0; n < 2; n++) {
      const int col = n0 + wn * 32 + n * 16 + lr;
      const float bgc = bgv[col], buc = buv[col];
#pragma unroll
      for (int r = 0; r < 4; r++) {
        float gv = accg[m][n][r] + bgc;
        float uv = accu[m][n][r] + buc;
        float sg = gv / (1.0f + __expf(-gv));
        out[(size_t)(row + r) * 8192 + col] = f2bf(sg * uv);
      }
    }
  }
}

// ---------------- Flash attention (causal, GQA kv = hq%4) ----------------
// 512 blocks, 4 waves each; wave w owns 32 q rows. KVBLK=64.
__global__ __launch_bounds__(256) void attn_kernel(const u16* __restrict__ QKV,
                                                   u16* __restrict__ O) {
  const int bid = blockIdx.x;
  const int half = bid >> 8, rr = bid & 255;
  const int bh = rr >> 3, tt = rr & 7;
  const int qtile = half ? (15 - tt) : tt;
  const int b = bh >> 4, hq = bh & 15, g = hq & 3;
  const int q0 = qtile * 128;
  const int tid = threadIdx.x, l = tid & 63, w = tid >> 6;
  const int lr = l & 15, lg = l >> 4;

  __shared__ u16 kT[64 * 128] __attribute__((aligned(16)));   // [t][d], d-chunk ^= (t&7)
  __shared__ u16 vT[128 * 64] __attribute__((aligned(16)));   // [d][t], t-chunk ^= (d^(d>>4))&7
  __shared__ u16 pT[4][32 * 72] __attribute__((aligned(16)));

  const float scale = 0.08838834764831845f;   // 1/sqrt(128)

  bf16x8 qF[2][4];
  const int qrow_base = b * S_LEN + q0 + w * 32;
#pragma unroll
  for (int mq = 0; mq < 2; mq++)
#pragma unroll
    for (int kk = 0; kk < 4; kk++)
      qF[mq][kk] = *(const bf16x8*)(QKV + (size_t)(qrow_base + mq * 16 + lr) * DQKV
                                    + hq * 128 + kk * 32 + lg * 8);

  f32x4 o_acc[2][8] = {};
  float m_run[2][4], l_run[2][4];
#pragma unroll
  for (int mq = 0; mq < 2; mq++)
#pragma unroll
    for (int r = 0; r < 4; r++) { m_run[mq][r] = -1e30f; l_run[mq][r] = 0.0f; }

  const int qmin_w = q0 + w * 32;
  const int nt = (q0 + 128) >> 6;

  for (int it = 0; it < nt; ++it) {
    const int t0 = it * 64;
    __syncthreads();
    {
      const int rbase = tid >> 3;          // 0..31
      const int c16 = (tid & 7) * 16;      // 0..112
#pragma unroll
      for (int pass = 0; pass < 2; ++pass) {
        const int r = rbase + pass * 32;
        const u16* src = QKV + (size_t)(b * S_LEN + t0 + r) * DQKV + 2048 + g * 128 + c16;
        const int rk = r & 7;
#pragma unroll
        for (int jj = 0; jj < 2; ++jj) {
          bf16x8 kv = *(const bf16x8*)(src + jj * 8);
          const int chunk = (c16 >> 3) + jj;
          *(bf16x8*)&kT[r * 128 + ((chunk ^ rk) << 3)] = kv;
        }
#pragma unroll
        for (int jj = 0; jj < 2; ++jj) {
          bf16x8 vv = *(const bf16x8*)(src + 512 + jj * 8);
#pragma unroll
          for (int j = 0; j < 8; ++j) {
            const int d = c16 + jj * 8 + j;
            const int key = (d ^ (d >> 4)) & 7;
            vT[d * 64 + (r & 7) + (((r >> 3) ^ key) << 3)] = (u16)vv[j];
          }
        }
      }
    }
    __syncthreads();

    if (t0 <= qmin_w + 31) {
      f32x4 sc[2][4] = {};
#pragma unroll
      for (int mt = 0; mt < 4; mt++) {
        const int tq = mt * 16 + lr;
        const int tk = tq & 7;
#pragma unroll
        for (int kk = 0; kk < 4; kk++) {
          bf16x8 kF = *(const bf16x8*)&kT[tq * 128 + (((kk * 4 + lg) ^ tk) << 3)];
          sc[0][mt] = __builtin_amdgcn_mfma_f32_16x16x32_bf16(qF[0][kk], kF, sc[0][mt], 0, 0, 0);
          sc[1][mt] = __builtin_amdgcn_mfma_f32_16x16x32_bf16(qF[1][kk], kF, sc[1][mt], 0, 0, 0);
        }
      }
      const bool needMask = (t0 + 63 > qmin_w);
#pragma unroll
      for (int mq = 0; mq < 2; mq++)
#pragma unroll
        for (int mt = 0; mt < 4; mt++)
#pragma unroll
          for (int r = 0; r < 4; r++) {
            float v = sc[mq][mt][r] * scale;
            if (needMask) {
              int qg = qmin_w + mq * 16 + lg * 4 + r;
              int tg = t0 + mt * 16 + lr;
              if (tg > qg) v = -1e30f;
            }
            sc[mq][mt][r] = v;
          }
#pragma unroll
      for (int mq = 0; mq < 2; mq++) {
        float al[4];
#pragma unroll
        for (int r = 0; r < 4; r++) {
          float tmax = fmaxf(fmaxf(sc[mq][0][r], sc[mq][1][r]),
                             fmaxf(sc[mq][2][r], sc[mq][3][r]));
#pragma unroll
          for (int m = 1; m < 16; m <<= 1) tmax = fmaxf(tmax, __shfl_xor(tmax, m, 64));
          float mn = fmaxf(m_run[mq][r], tmax);
          float a = __expf(m_run[mq][r] - mn);
          m_run[mq][r] = mn;
          float rs = 0.0f;
#pragma unroll
          for (int mt = 0; mt < 4; mt++) {
            float pv = __expf(sc[mq][mt][r] - mn);
            sc[mq][mt][r] = pv;
            rs += pv;
          }
#pragma unroll
          for (int m = 1; m < 16; m <<= 1) rs += __shfl_xor(rs, m, 64);
          l_run[mq][r] = l_run[mq][r] * a + rs;
          al[r] = a;
        }
#pragma unroll
        for (int n = 0; n < 8; n++)
#pragma unroll
          for (int r = 0; r < 4; r++) o_acc[mq][n][r] *= al[r];
#pragma unroll
        for (int mt = 0; mt < 4; mt++)
#pragma unroll
          for (int r = 0; r < 4; r++)
            pT[w][(mq * 16 + lg * 4 + r) * 72 + mt * 16 + lr] = f2bf(sc[mq][mt][r]);
      }
      bf16x8 pF[2][2];
#pragma unroll
      for (int mq = 0; mq < 2; mq++)
#pragma unroll
        for (int kt = 0; kt < 2; kt++)
          pF[mq][kt] = *(const bf16x8*)&pT[w][(mq * 16 + lr) * 72 + kt * 32 + lg * 8];
#pragma unroll
      for (int kt = 0; kt < 2; kt++)
#pragma unroll
        for (int n = 0; n < 8; n++) {
          const int d = n * 16 + lr;
          const int key = (d ^ (d >> 4)) & 7;
          bf16x8 vF = *(const bf16x8*)&vT[d * 64 + (((kt * 4 + lg) ^ key) << 3)];
          o_acc[0][n] = __builtin_amdgcn_mfma_f32_16x16x32_bf16(pF[0][kt], vF, o_acc[0][n], 0, 0, 0);
          o_acc[1][n] = __builtin_amdgcn_mfma_f32_16x16x32_bf16(pF[1][kt], vF, o_acc[1][n], 0, 0, 0);
        }
    }
  }
#pragma unroll
  for (int mq = 0; mq < 2; mq++)
#pragma unroll
    for (int n = 0; n < 8; n++)
#pragma unroll
      for (int r = 0; r < 4; r++) {
        float v = o_acc[mq][n][r] / l_run[mq][r];
        int row = b * S_LEN + q0 + w * 32 + mq * 16 + lg * 4 + r;
        int col = hq * 128 + n * 16 + lr;
        O[(size_t)row * 2048 + col] = f2bf(v);
      }
}

// ---------------- launch ----------------
extern "C" void kernel_launch(void* const* d_in, const int* in_sizes, int n_in,
                              void* d_out, int out_size, void* d_ws, size_t ws_size,
                              hipStream_t stream) {
  const float* x  = (const float*)d_in[0];
  const float* Wq = (const float*)d_in[2];
  const float* Wk = (const float*)d_in[3];
  const float* Wv = (const float*)d_in[4];
  const float* Wo = (const float*)d_in[5];
  const float* Wg = (const float*)d_in[6];
  const float* bg = (const float*)d_in[7];
  const float* Wu = (const float*)d_in[8];
  const float* bu = (const float*)d_in[9];
  const float* Wd = (const float*)d_in[10];
  const float* bd = (const float*)d_in[11];
  const float* g1 = (const float*)d_in[12];
  const float* g2 = (const float*)d_in[13];

  char* p = (char*)d_ws;
  auto alloc = [&](size_t bytes) { char* r = p; p += (bytes + 255) & ~(size_t)255; return r; };
  u16*   BtQKV = (u16*)alloc((size_t)DQKV * 2048 * 2);
  u16*   WoT   = (u16*)alloc((size_t)2048 * 2048 * 2);
  u16*   WgT   = (u16*)alloc((size_t)8192 * 2048 * 2);
  u16*   WuT   = (u16*)alloc((size_t)8192 * 2048 * 2);
  u16*   WdT   = (u16*)alloc((size_t)2048 * 8192 * 2);
  u16*   xn    = (u16*)alloc((size_t)NROW * 2048 * 2);   // also hn
  u16*   QKV   = (u16*)alloc((size_t)NROW * DQKV * 2);
  u16*   Obuf  = (u16*)alloc((size_t)NROW * 2048 * 2);
  float* h     = (float*)alloc((size_t)NROW * 2048 * 4);
  u16*   gact  = (u16*)alloc((size_t)NROW * 8192 * 2);
  float* cosT  = (float*)alloc((size_t)S_LEN * 64 * 4);
  float* sinT  = (float*)alloc((size_t)S_LEN * 64 * 4);

  dim3 tb(32, 8);
  transpose_f32_bf16<<<dim3(2048/32, 2048/32), tb, 0, stream>>>(Wq, BtQKV,                    2048, 2048);
  transpose_f32_bf16<<<dim3( 512/32, 2048/32), tb, 0, stream>>>(Wk, BtQKV + 2048ull*2048,     2048,  512);
  transpose_f32_bf16<<<dim3( 512/32, 2048/32), tb, 0, stream>>>(Wv, BtQKV + 2560ull*2048,     2048,  512);
  transpose_f32_bf16<<<dim3(2048/32, 2048/32), tb, 0, stream>>>(Wo, WoT,                      2048, 2048);
  transpose_f32_bf16<<<dim3(8192/32, 2048/32), tb, 0, stream>>>(Wg, WgT,                      2048, 8192);
  transpose_f32_bf16<<<dim3(8192/32, 2048/32), tb, 0, stream>>>(Wu, WuT,                      2048, 8192);
  transpose_f32_bf16<<<dim3(2048/32, 8192/32), tb, 0, stream>>>(Wd, WdT,                      8192, 2048);

  rope_tables<<<(S_LEN * 64) / 256, 256, 0, stream>>>(cosT, sinT);

  rmsnorm_kernel<<<NROW, 256, 0, stream>>>(x, g1, xn);

  gemm256<256, 0><<<192, 512, 0, stream>>>(xn, BtQKV, 12, 2048, 3072,
                                           nullptr, nullptr, QKV, nullptr);

  rope_apply<<<(NROW * 20 * 64) / 256, 256, 0, stream>>>(QKV, cosT, sinT);

  attn_kernel<<<512, 256, 0, stream>>>(QKV, Obuf);

  gemm256<128, 1><<<256, 512, 0, stream>>>(Obuf, WoT, 16, 2048, 2048,
                                           nullptr, x, nullptr, h);

  rmsnorm_kernel<<<NROW, 256, 0, stream>>>(h, g2, xn);

  swiglu_gemm<<<1024, 512, 0, stream>>>(xn, WgT, WuT, 64, 2048, bg, bu, gact);

  gemm256<128, 1><<<256, 512, 0, stream>>>(gact, WdT, 16, 8192, 2048,
                                           bd, h, nullptr, (float*)d_out);
}